// Round 1
// baseline (759.025 us; speedup 1.0000x reference)
//
#include <hip/hip_runtime.h>

#define N_FIELDS 26
#define EMB      64
#define BATCH    16384
#define VOCAB    100000

#define BB     8                    // batch elements per block
#define BLOCK  256
#define PER_B  (EMB * N_FIELDS)     // 1664 floats of output per batch element
#define ROWS   (N_FIELDS * BB)      // 208 gathered rows per block
#define QUADS  (EMB / 4)            // 16 float4 per row
#define TOT4   (ROWS * QUADS)       // 3328 float4 per block
#define ITERS  (TOT4 / BLOCK)       // 13

__global__ __launch_bounds__(BLOCK) void sparse_encoder_gather(
    const int*   __restrict__ idx,   // [N_FIELDS][BATCH]
    const float* __restrict__ W,     // [N_FIELDS][VOCAB][EMB]
    float*       __restrict__ out)   // [BATCH][EMB][N_FIELDS]
{
    __shared__ float tile[BB * PER_B];   // output-order staging: [bl][e][f]
    __shared__ int   s_idx[ROWS];        // row -> vocab index, row = f*BB + bl

    const int tid = threadIdx.x;
    const int b0  = blockIdx.x * BB;

    if (tid < ROWS) {
        const int f  = tid / BB;
        const int bl = tid % BB;
        s_idx[tid] = idx[f * BATCH + b0 + bl];
    }
    __syncthreads();

    // ---- gather phase: coalesced 256B-row reads, 16 lanes x float4 per row ----
    float4 v[ITERS];
#pragma unroll
    for (int k = 0; k < ITERS; ++k) {
        const int w   = k * BLOCK + tid;
        const int row = w >> 4;          // which (f, bl) row
        const int q   = w & 15;          // which float4 within the 64-float row
        const int f   = row / BB;
        // all offsets < 2^31 elements: 26*100000*64 = 166.4M
        const int roff = f * (VOCAB * EMB) + s_idx[row] * EMB + q * 4;
        v[k] = *reinterpret_cast<const float4*>(W + roff);
    }

    // ---- transpose into LDS in exact output layout [bl][e][f] ----
#pragma unroll
    for (int k = 0; k < ITERS; ++k) {
        const int w   = k * BLOCK + tid;
        const int row = w >> 4;
        const int q   = w & 15;
        const int f   = row / BB;
        const int bl  = row % BB;
        float* t = &tile[bl * PER_B + (q * 4) * N_FIELDS + f];
        t[0 * N_FIELDS] = v[k].x;
        t[1 * N_FIELDS] = v[k].y;
        t[2 * N_FIELDS] = v[k].z;
        t[3 * N_FIELDS] = v[k].w;
    }
    __syncthreads();

    // ---- flush: contiguous float4 stream, perfectly coalesced ----
    const float4* t4 = reinterpret_cast<const float4*>(tile);
    float4*       o4 = reinterpret_cast<float4*>(out + (long long)b0 * PER_B);
#pragma unroll
    for (int k = 0; k < ITERS; ++k) {
        o4[k * BLOCK + tid] = t4[k * BLOCK + tid];
    }
}

extern "C" void kernel_launch(void* const* d_in, const int* in_sizes, int n_in,
                              void* d_out, int out_size, void* d_ws, size_t ws_size,
                              hipStream_t stream) {
    const int*   idx = (const int*)d_in[0];    // (26, 16384) int32
    const float* W   = (const float*)d_in[1];  // (26, 100000, 64) fp32
    float*       out = (float*)d_out;          // (16384, 64, 26) fp32

    sparse_encoder_gather<<<BATCH / BB, BLOCK, 0, stream>>>(idx, W, out);
}